// Round 8
// baseline (181.779 us; speedup 1.0000x reference)
//
#include <hip/hip_runtime.h>
#include <hip/hip_fp16.h>

#define HH 384
#define WW 384
#define HW (HH * WW)            // 147456
#define NIMG 128                // B*G
#define NPIX (NIMG * HW)        // 18874368
#define GRAD_CNT 37650432.0

// K1: full-width tiles, 8 rows, +/-3 staged margin, 14 rows in LDS (23.97 KB)
#define K1_TH 8
#define K1_M  3
#define K1_NT (HH / K1_TH)              // 48
#define K1_SROWS (K1_TH + 2 * K1_M)     // 14
#define K1_LS 428                       // skewed row stride (floats)
#define NP_G (K1_NT * NIMG)             // 6144

// K2: n-split into 4 partial template planes
#define K2_SPLIT 4

// K3 tiling: 32x32 tiles, 256 threads, 4 px/thread
#define K3_T 32
#define K3_NX (WW / K3_T)               // 12
#define K3_TILES (K3_NX * (HH / K3_T)) // 144
#define K3_LS 40                        // LDS row stride (floats, 16B-aligned)
#define NP_N (K3_TILES * NIMG)          // 18432

// skewed offset for scalar element x (float index within a row)
__device__ inline int skew_off(int x) {
    int g = x >> 2;
    return 4 * (g + (g >> 3)) + (x & 3);
}

// ---- block reduction (256 threads = 4 waves) -------------------------------
__device__ inline void block_reduce_store_256(float v, float* dst) {
    #pragma unroll
    for (int o = 32; o > 0; o >>= 1) v += __shfl_down(v, o);
    __shared__ float s[4];
    int wave = threadIdx.x >> 6, lane = threadIdx.x & 63;
    if (lane == 0) s[wave] = v;
    __syncthreads();
    if (threadIdx.x == 0) *dst = s[0] + s[1] + s[2] + s[3];
}

// ---- K1: bilinear warp (LDS gather, prefetched flow, fp16 out) + grad ------
__global__ __launch_bounds__(256, 6) void warp_grad_kernel(
        const float* __restrict__ images, const float* __restrict__ warps,
        __half* __restrict__ warped, float* __restrict__ partialsG) {
    __shared__ float simg[K1_SROWS * K1_LS];  // 23.97 KB
    int n = blockIdx.y;
    int yt = blockIdx.x;
    int y0 = yt * K1_TH;
    int ys0 = max(0, y0 - K1_M);
    int ys1 = min(HH - 1, y0 + K1_TH - 1 + K1_M);
    const float* img = images + (size_t)n * HW;
    int tid = threadIdx.x;
    int cnt = ys1 - ys0 + 1;                  // <= 14

    // stage rows [ys0, ys1]: coalesced float4 read, skewed 16B-aligned write
    for (int i = tid; i < cnt * 96; i += 256) {
        int r = i / 96, gg = i - r * 96;
        float4 v = *(const float4*)(img + (ys0 + r) * WW + gg * 4);
        *(float4*)(simg + r * K1_LS + 4 * (gg + (gg >> 3))) = v;
    }

    const float* flow0 = warps + (size_t)n * 2 * HW;
    const float* flow1 = flow0 + HW;

    // ---- phase A: prefetch ALL flow data (max MLP, branchless edges) ----
    float4 f0v[3], f1v[3], b0v[3], b1v[3];
    float a0v[3], a1v[3];
    int xv[3], yv[3], basev[3];
    #pragma unroll
    for (int gi = 0; gi < 3; ++gi) {
        int p4 = gi * 256 + tid;
        int r = p4 / 96;
        int c4 = p4 - r * 96;
        int x0 = c4 * 4;
        int y = y0 + r;
        int base = y * WW + x0;
        xv[gi] = x0; yv[gi] = y; basev[gi] = base;
        f0v[gi] = *(const float4*)(flow0 + base);
        f1v[gi] = *(const float4*)(flow1 + base);
        int offR = (x0 + 4 < WW) ? 4 : 3;         // self-zeroing edge diff
        a0v[gi] = flow0[base + offR];
        a1v[gi] = flow1[base + offR];
        int offD = (y + 1 < HH) ? WW : 0;         // self-zeroing edge diff
        b0v[gi] = *(const float4*)(flow0 + base + offD);
        b1v[gi] = *(const float4*)(flow1 + base + offD);
    }
    __syncthreads();                               // staging complete

    float g = 0.f;
    #pragma unroll
    for (int gi = 0; gi < 3; ++gi) {
        float4 f0 = f0v[gi], f1 = f1v[gi], b0 = b0v[gi], b1 = b1v[gi];
        int x0 = xv[gi], y = yv[gi], base = basev[gi];

        // grad2d l2: dx within group + right neighbor, dy vs next row
        float d;
        d = f0.y - f0.x; g += d * d;  d = f1.y - f1.x; g += d * d;
        d = f0.z - f0.y; g += d * d;  d = f1.z - f1.y; g += d * d;
        d = f0.w - f0.z; g += d * d;  d = f1.w - f1.z; g += d * d;
        d = a0v[gi] - f0.w; g += d * d;  d = a1v[gi] - f1.w; g += d * d;
        d = b0.x - f0.x; g += d * d;  d = b1.x - f1.x; g += d * d;
        d = b0.y - f0.y; g += d * d;  d = b1.y - f1.y; g += d * d;
        d = b0.z - f0.z; g += d * d;  d = b1.z - f1.z; g += d * d;
        d = b0.w - f0.w; g += d * d;  d = b1.w - f1.w; g += d * d;

        float fxa[4] = {f0.x, f0.y, f0.z, f0.w};
        float fya[4] = {f1.x, f1.y, f1.z, f1.w};
        float o[4];
        #pragma unroll
        for (int j = 0; j < 4; ++j) {
            float cx = (float)(x0 + j) + fxa[j];
            float cy = (float)y + fya[j];
            float flx = floorf(cx), fly = floorf(cy);
            float wx = cx - flx, wy = cy - fly;
            int xi = (int)flx, yi = (int)fly;
            int x0c = min(max(xi, 0), WW - 1), x1c = min(max(xi + 1, 0), WW - 1);
            int y0c = min(max(yi, 0), HH - 1), y1c = min(max(yi + 1, 0), HH - 1);
            float v00, v01, v10, v11;
            if (y0c >= ys0 && y1c <= ys1) {   // ~always (P(miss)~3.6e-4): LDS
                const float* r0 = simg + (y0c - ys0) * K1_LS;
                const float* r1 = simg + (y1c - ys0) * K1_LS;
                int oa = skew_off(x0c), ob = skew_off(x1c);
                v00 = r0[oa]; v01 = r0[ob];
                v10 = r1[oa]; v11 = r1[ob];
            } else {                          // rare: exact global fallback
                v00 = img[y0c * WW + x0c]; v01 = img[y0c * WW + x1c];
                v10 = img[y1c * WW + x0c]; v11 = img[y1c * WW + x1c];
            }
            float top = v00 + wx * (v01 - v00);
            float bot = v10 + wx * (v11 - v10);
            o[j] = top + wy * (bot - top);
        }
        union { __half2 h2[2]; uint2 u; } cv;
        cv.h2[0] = __floats2half2_rn(o[0], o[1]);
        cv.h2[1] = __floats2half2_rn(o[2], o[3]);
        *(uint2*)(warped + (size_t)n * HW + base) = cv.u;
    }
    block_reduce_store_256(g, &partialsG[(size_t)n * K1_NT + yt]);
}

// ---- K2a: partial template sums (n split 4-ways, fp16 in) ------------------
__global__ __launch_bounds__(256) void template_part_kernel(
        const __half* __restrict__ warped, float* __restrict__ tpart) {
    int p4 = blockIdx.x * 256 + threadIdx.x;      // < HW/4
    int q = blockIdx.y;                           // 0..3
    const __half* p = warped + (size_t)q * (NIMG / K2_SPLIT) * HW + p4 * 4;
    float4 s = {0.f, 0.f, 0.f, 0.f};
    #pragma unroll 8
    for (int nn = 0; nn < NIMG / K2_SPLIT; ++nn) {
        union { uint2 u; __half2 h2[2]; } cv;
        cv.u = *(const uint2*)(p + (size_t)nn * HW);
        float2 lo = __half22float2(cv.h2[0]);
        float2 hi = __half22float2(cv.h2[1]);
        s.x += lo.x; s.y += lo.y; s.z += hi.x; s.w += hi.y;
    }
    *(float4*)(tpart + (size_t)q * HW + p4 * 4) = s;
}

// ---- K2b: combine partials -> template (f32) -------------------------------
__global__ __launch_bounds__(256) void template_combine_kernel(
        const float* __restrict__ tpart, float* __restrict__ templ) {
    int p4 = blockIdx.x * 256 + threadIdx.x;      // < HW/4
    float4 a = *(const float4*)(tpart + p4 * 4);
    float4 b = *(const float4*)(tpart + HW + p4 * 4);
    float4 c = *(const float4*)(tpart + 2 * HW + p4 * 4);
    float4 e = *(const float4*)(tpart + 3 * HW + p4 * 4);
    const float sc = 1.f / (float)NIMG;
    float4 s;
    s.x = (a.x + b.x + c.x + e.x) * sc;
    s.y = (a.y + b.y + c.y + e.y) * sc;
    s.z = (a.z + b.z + c.z + e.z) * sc;
    s.w = (a.w + b.w + c.w + e.w) * sc;
    *(float4*)(templ + p4 * 4) = s;
}

// ---- K3: LNCC per (n, 32x32 tile), vectorized LDS sliding window -----------
__global__ __launch_bounds__(256) void lncc_kernel(
        const __half* __restrict__ warped, const float* __restrict__ templ,
        float* __restrict__ partialsN) {
    __shared__ float st[34][K3_LS];
    __shared__ float sp[34][K3_LS];
    int n = blockIdx.y;
    int tile = blockIdx.x;
    int tyt = tile / K3_NX, txt = tile - tyt * K3_NX;
    int oy0 = tyt * K3_T, ox0 = txt * K3_T;
    const __half* t = warped + (size_t)n * HW;
    int tid = threadIdx.x;

    for (int i = tid; i < 34 * 34; i += 256) {
        int ly = i / 34, lx = i - ly * 34;
        int gy = oy0 + ly - 1, gx = ox0 + lx - 1;
        bool ok = (gy >= 0) & (gy < HH) & (gx >= 0) & (gx < WW);
        int gidx = gy * WW + gx;
        st[ly][lx] = ok ? __half2float(t[gidx]) : 0.f;
        sp[ly][lx] = ok ? templ[gidx] : 0.f;
    }
    __syncthreads();

    int tx = tid & 7, ty = tid >> 3;   // ty: output row 0..31, xb: x base
    int xb = tx * 4;
    float cT[6] = {0,0,0,0,0,0}, cP[6] = {0,0,0,0,0,0};
    float cT2[6] = {0,0,0,0,0,0}, cP2[6] = {0,0,0,0,0,0}, cTP[6] = {0,0,0,0,0,0};
    #pragma unroll
    for (int r = 0; r < 3; ++r) {
        float4 t4 = *(const float4*)&st[ty + r][xb];      // 16B aligned
        float2 t2 = *(const float2*)&st[ty + r][xb + 4];
        float4 p4 = *(const float4*)&sp[ty + r][xb];
        float2 p2 = *(const float2*)&sp[ty + r][xb + 4];
        float tv[6] = {t4.x, t4.y, t4.z, t4.w, t2.x, t2.y};
        float pv[6] = {p4.x, p4.y, p4.z, p4.w, p2.x, p2.y};
        #pragma unroll
        for (int c = 0; c < 6; ++c) {
            cT[c] += tv[c]; cP[c] += pv[c];
            cT2[c] = fmaf(tv[c], tv[c], cT2[c]);
            cP2[c] = fmaf(pv[c], pv[c], cP2[c]);
            cTP[c] = fmaf(tv[c], pv[c], cTP[c]);
        }
    }
    const float inv9 = 1.f / 9.f;
    float nccsum = 0.f;
    #pragma unroll
    for (int j = 0; j < 4; ++j) {
        float ts = cT[j] + cT[j + 1] + cT[j + 2];
        float ps = cP[j] + cP[j + 1] + cP[j + 2];
        float t2s = cT2[j] + cT2[j + 1] + cT2[j + 2];
        float p2s = cP2[j] + cP2[j + 1] + cP2[j + 2];
        float tps = cTP[j] + cTP[j + 1] + cTP[j + 2];
        float cross = tps - (ps * inv9) * ts;
        float tvar = fmaxf(t2s - (ts * inv9) * ts, 0.f);
        float pvar = fmaxf(p2s - (ps * inv9) * ps, 0.f);
        nccsum += (cross * cross) / (tvar * pvar + 1e-5f);
    }
    block_reduce_store_256(nccsum, &partialsN[(size_t)n * K3_TILES + tile]);
}

// ---- K4: final reduction (double) ------------------------------------------
__global__ __launch_bounds__(1024) void finalize_kernel(
        const float* __restrict__ pN, const float* __restrict__ pG,
        float* __restrict__ out) {
    double accN = 0.0, accG = 0.0;
    for (int i = threadIdx.x; i < NP_N; i += 1024) accN += (double)pN[i];
    for (int i = threadIdx.x; i < NP_G; i += 1024) accG += (double)pG[i];
    #pragma unroll
    for (int o = 32; o > 0; o >>= 1) {
        accN += __shfl_down(accN, o);
        accG += __shfl_down(accG, o);
    }
    __shared__ double sN[16], sG[16];
    int wave = threadIdx.x >> 6, lane = threadIdx.x & 63;
    if (lane == 0) { sN[wave] = accN; sG[wave] = accG; }
    __syncthreads();
    if (threadIdx.x == 0) {
        double tN = 0.0, tG = 0.0;
        #pragma unroll
        for (int w = 0; w < 16; ++w) { tN += sN[w]; tG += sG[w]; }
        double lncc = -(tN / (double)NPIX);
        double g2 = tG / (2.0 * GRAD_CNT);
        out[0] = (float)(lncc + g2);
    }
}

extern "C" void kernel_launch(void* const* d_in, const int* in_sizes, int n_in,
                              void* d_out, int out_size, void* d_ws, size_t ws_size,
                              hipStream_t stream) {
    const float* images = (const float*)d_in[0];
    const float* warps  = (const float*)d_in[1];
    float* out = (float*)d_out;

    __half* warped  = (__half*)d_ws;                             // NPIX halves
    float* fbase    = (float*)((char*)d_ws + (size_t)NPIX * 2);
    float* templ     = fbase;                     // HW floats
    float* partialsN = templ + HW;                // NP_N floats
    float* partialsG = partialsN + NP_N;          // NP_G floats
    float* tpart     = partialsG + NP_G;          // 4*HW floats

    warp_grad_kernel<<<dim3(K1_NT, NIMG), dim3(256), 0, stream>>>(
        images, warps, warped, partialsG);
    template_part_kernel<<<dim3(HW / 4 / 256, K2_SPLIT), dim3(256), 0, stream>>>(
        warped, tpart);
    template_combine_kernel<<<dim3(HW / 4 / 256), dim3(256), 0, stream>>>(
        tpart, templ);
    lncc_kernel<<<dim3(K3_TILES, NIMG), dim3(256), 0, stream>>>(
        warped, templ, partialsN);
    finalize_kernel<<<dim3(1), dim3(1024), 0, stream>>>(
        partialsN, partialsG, out);
}

// Round 9
// 131.803 us; speedup vs baseline: 1.3792x; 1.3792x over previous
//
#include <hip/hip_runtime.h>
#include <hip/hip_fp16.h>

#define HH 384
#define WW 384
#define HW (HH * WW)            // 147456
#define NIMG 128                // B*G
#define NPIX (NIMG * HW)        // 18874368
#define GRAD_CNT 37650432.0

// K1: full-width tiles, 8 rows, +/-3 staged margin, 14 rows in LDS (23.97 KB)
#define K1_TH 8
#define K1_M  3
#define K1_NT (HH / K1_TH)              // 48
#define K1_SROWS (K1_TH + 2 * K1_M)     // 14
#define K1_LS 428                       // skewed row stride (floats)
#define NP_G (K1_NT * NIMG)             // 6144

// K2: n-split into 4 partial template planes
#define K2_SPLIT 4

// K3 tiling: 32x32 tiles, 256 threads, 4 px/thread; staged window 40 cols
#define K3_T 32
#define K3_NX (WW / K3_T)               // 12
#define K3_TILES (K3_NX * (HH / K3_T)) // 144
#define NP_N (K3_TILES * NIMG)          // 18432

// skewed offset for scalar element x (float index within a row)
__device__ inline int skew_off(int x) {
    int g = x >> 2;
    return 4 * (g + (g >> 3)) + (x & 3);
}

// ---- block reduction (256 threads = 4 waves) -------------------------------
__device__ inline void block_reduce_store_256(float v, float* dst) {
    #pragma unroll
    for (int o = 32; o > 0; o >>= 1) v += __shfl_down(v, o);
    __shared__ float s[4];
    int wave = threadIdx.x >> 6, lane = threadIdx.x & 63;
    if (lane == 0) s[wave] = v;
    __syncthreads();
    if (threadIdx.x == 0) *dst = s[0] + s[1] + s[2] + s[3];
}

// ---- K1: bilinear warp (skewed LDS gather, float4 streams, fp16 out) -------
// Round-7 structure (interleaved per-group loads preserve f/b row L1 reuse).
__global__ __launch_bounds__(256, 6) void warp_grad_kernel(
        const float* __restrict__ images, const float* __restrict__ warps,
        __half* __restrict__ warped, float* __restrict__ partialsG) {
    __shared__ float simg[K1_SROWS * K1_LS];  // 23.97 KB
    int n = blockIdx.y;
    int yt = blockIdx.x;
    int y0 = yt * K1_TH;
    int ys0 = max(0, y0 - K1_M);
    int ys1 = min(HH - 1, y0 + K1_TH - 1 + K1_M);
    int cnt = ys1 - ys0 + 1;                  // <= 14
    const float* img = images + (size_t)n * HW;
    int tid = threadIdx.x;

    // stage rows [ys0, ys1]: coalesced float4 read, skewed 16B-aligned write
    for (int i = tid; i < cnt * 96; i += 256) {
        int r = i / 96, gg = i - r * 96;
        float4 v = *(const float4*)(img + (ys0 + r) * WW + gg * 4);
        *(float4*)(simg + r * K1_LS + 4 * (gg + (gg >> 3))) = v;
    }
    __syncthreads();

    const float* flow0 = warps + (size_t)n * 2 * HW;
    const float* flow1 = flow0 + HW;
    float g = 0.f;

    #pragma unroll
    for (int gi = 0; gi < 3; ++gi) {          // 8 rows * 96 groups = 3 * 256
        int p4 = gi * 256 + tid;
        int r = p4 / 96;                      // tile row 0..7
        int c4 = p4 - r * 96;
        int x0 = c4 * 4;
        int y = y0 + r;
        int base = y * WW + x0;

        float4 f0 = *(const float4*)(flow0 + base);
        float4 f1 = *(const float4*)(flow1 + base);

        // grad2d l2: dx within group + right neighbor, dy vs next row
        float d;
        d = f0.y - f0.x; g += d * d;  d = f1.y - f1.x; g += d * d;
        d = f0.z - f0.y; g += d * d;  d = f1.z - f1.y; g += d * d;
        d = f0.w - f0.z; g += d * d;  d = f1.w - f1.z; g += d * d;
        if (x0 + 4 < WW) {
            float a0 = flow0[base + 4], a1 = flow1[base + 4];
            d = a0 - f0.w; g += d * d;  d = a1 - f1.w; g += d * d;
        }
        if (y + 1 < HH) {
            float4 b0 = *(const float4*)(flow0 + base + WW);
            float4 b1 = *(const float4*)(flow1 + base + WW);
            d = b0.x - f0.x; g += d * d;  d = b1.x - f1.x; g += d * d;
            d = b0.y - f0.y; g += d * d;  d = b1.y - f1.y; g += d * d;
            d = b0.z - f0.z; g += d * d;  d = b1.z - f1.z; g += d * d;
            d = b0.w - f0.w; g += d * d;  d = b1.w - f1.w; g += d * d;
        }

        float fxa[4] = {f0.x, f0.y, f0.z, f0.w};
        float fya[4] = {f1.x, f1.y, f1.z, f1.w};
        float o[4];
        #pragma unroll
        for (int j = 0; j < 4; ++j) {
            float cx = (float)(x0 + j) + fxa[j];
            float cy = (float)y + fya[j];
            float flx = floorf(cx), fly = floorf(cy);
            float wx = cx - flx, wy = cy - fly;
            int xi = (int)flx, yi = (int)fly;
            int x0c = min(max(xi, 0), WW - 1), x1c = min(max(xi + 1, 0), WW - 1);
            int y0c = min(max(yi, 0), HH - 1), y1c = min(max(yi + 1, 0), HH - 1);
            float v00, v01, v10, v11;
            if (y0c >= ys0 && y1c <= ys1) {   // ~always: LDS gather
                const float* r0 = simg + (y0c - ys0) * K1_LS;
                const float* r1 = simg + (y1c - ys0) * K1_LS;
                int oa = skew_off(x0c), ob = skew_off(x1c);
                v00 = r0[oa]; v01 = r0[ob];
                v10 = r1[oa]; v11 = r1[ob];
            } else {                          // rare: exact global fallback
                v00 = img[y0c * WW + x0c]; v01 = img[y0c * WW + x1c];
                v10 = img[y1c * WW + x0c]; v11 = img[y1c * WW + x1c];
            }
            float top = v00 + wx * (v01 - v00);
            float bot = v10 + wx * (v11 - v10);
            o[j] = top + wy * (bot - top);
        }
        union { __half2 h2[2]; uint2 u; } cv;
        cv.h2[0] = __floats2half2_rn(o[0], o[1]);
        cv.h2[1] = __floats2half2_rn(o[2], o[3]);
        *(uint2*)(warped + (size_t)n * HW + base) = cv.u;
    }
    block_reduce_store_256(g, &partialsG[(size_t)n * K1_NT + yt]);
}

// ---- K2a: partial template sums (n split 4-ways, fp16 in, f32 out) ---------
__global__ __launch_bounds__(256) void template_part_kernel(
        const __half* __restrict__ warped, float* __restrict__ tpart) {
    int p4 = blockIdx.x * 256 + threadIdx.x;      // < HW/4
    int q = blockIdx.y;                           // 0..3
    const __half* p = warped + (size_t)q * (NIMG / K2_SPLIT) * HW + p4 * 4;
    float4 s = {0.f, 0.f, 0.f, 0.f};
    #pragma unroll 8
    for (int nn = 0; nn < NIMG / K2_SPLIT; ++nn) {
        union { uint2 u; __half2 h2[2]; } cv;
        cv.u = *(const uint2*)(p + (size_t)nn * HW);
        float2 lo = __half22float2(cv.h2[0]);
        float2 hi = __half22float2(cv.h2[1]);
        s.x += lo.x; s.y += lo.y; s.z += hi.x; s.w += hi.y;
    }
    *(float4*)(tpart + (size_t)q * HW + p4 * 4) = s;
}

// ---- K3: LNCC per (n, 32x32 tile); fully vectorized 40-col staged window ---
// Staged cols s=0..39 <-> gx = ox0-4+s. Output col xc uses s = xc+3..xc+5.
// templ computed on the fly from the 4 tpart planes (L2/L3-resident).
__global__ __launch_bounds__(256) void lncc_kernel(
        const __half* __restrict__ warped, const float* __restrict__ tpart,
        float* __restrict__ partialsN) {
    __shared__ float st[34][40];
    __shared__ float sp[34][40];
    int n = blockIdx.y;
    int tile = blockIdx.x;
    int tyt = tile / K3_NX, txt = tile - tyt * K3_NX;
    int oy0 = tyt * K3_T, ox0 = txt * K3_T;
    const __half* t = warped + (size_t)n * HW;
    int tid = threadIdx.x;
    const float invN = 1.f / (float)NIMG;

    for (int i = tid; i < 34 * 10; i += 256) {
        int ly = i / 10, c = i - (i / 10) * 10;
        int gy = oy0 + ly - 1;
        int gx = ox0 - 4 + c * 4;                 // 8B/16B-aligned chunks
        float4 tv = {0.f, 0.f, 0.f, 0.f}, pv = {0.f, 0.f, 0.f, 0.f};
        if (gy >= 0 && gy < HH && gx >= 0 && gx + 3 < WW) {
            union { uint2 u; __half2 h2[2]; } cv;
            cv.u = *(const uint2*)(t + gy * WW + gx);
            float2 lo = __half22float2(cv.h2[0]);
            float2 hi = __half22float2(cv.h2[1]);
            tv = make_float4(lo.x, lo.y, hi.x, hi.y);
            const float* q = tpart + gy * WW + gx;
            float4 a = *(const float4*)q;
            float4 b = *(const float4*)(q + HW);
            float4 c2 = *(const float4*)(q + 2 * HW);
            float4 e = *(const float4*)(q + 3 * HW);
            pv = make_float4((a.x + b.x + c2.x + e.x) * invN,
                             (a.y + b.y + c2.y + e.y) * invN,
                             (a.z + b.z + c2.z + e.z) * invN,
                             (a.w + b.w + c2.w + e.w) * invN);
        }
        *(float4*)&st[ly][c * 4] = tv;
        *(float4*)&sp[ly][c * 4] = pv;
    }
    __syncthreads();

    int tx = tid & 7, ty = tid >> 3;   // ty: output row 0..31, xb: x base
    int xb = tx * 4;
    float cT[6] = {0,0,0,0,0,0}, cP[6] = {0,0,0,0,0,0};
    float cT2[6] = {0,0,0,0,0,0}, cP2[6] = {0,0,0,0,0,0}, cTP[6] = {0,0,0,0,0,0};
    #pragma unroll
    for (int r = 0; r < 3; ++r) {
        float t0 = st[ty + r][xb + 3];
        float4 t4 = *(const float4*)&st[ty + r][xb + 4];  // 16B aligned
        float t5 = st[ty + r][xb + 8];
        float p0 = sp[ty + r][xb + 3];
        float4 p4 = *(const float4*)&sp[ty + r][xb + 4];
        float p5 = sp[ty + r][xb + 8];
        float tv[6] = {t0, t4.x, t4.y, t4.z, t4.w, t5};
        float pv[6] = {p0, p4.x, p4.y, p4.z, p4.w, p5};
        #pragma unroll
        for (int c = 0; c < 6; ++c) {
            cT[c] += tv[c]; cP[c] += pv[c];
            cT2[c] = fmaf(tv[c], tv[c], cT2[c]);
            cP2[c] = fmaf(pv[c], pv[c], cP2[c]);
            cTP[c] = fmaf(tv[c], pv[c], cTP[c]);
        }
    }
    const float inv9 = 1.f / 9.f;
    float nccsum = 0.f;
    #pragma unroll
    for (int j = 0; j < 4; ++j) {
        float ts = cT[j] + cT[j + 1] + cT[j + 2];
        float ps = cP[j] + cP[j + 1] + cP[j + 2];
        float t2s = cT2[j] + cT2[j + 1] + cT2[j + 2];
        float p2s = cP2[j] + cP2[j + 1] + cP2[j + 2];
        float tps = cTP[j] + cTP[j + 1] + cTP[j + 2];
        float cross = tps - (ps * inv9) * ts;
        float tvar = fmaxf(t2s - (ts * inv9) * ts, 0.f);
        float pvar = fmaxf(p2s - (ps * inv9) * ps, 0.f);
        nccsum += (cross * cross) / (tvar * pvar + 1e-5f);
    }
    block_reduce_store_256(nccsum, &partialsN[(size_t)n * K3_TILES + tile]);
}

// ---- K4: final reduction (double) ------------------------------------------
__global__ __launch_bounds__(1024) void finalize_kernel(
        const float* __restrict__ pN, const float* __restrict__ pG,
        float* __restrict__ out) {
    double accN = 0.0, accG = 0.0;
    for (int i = threadIdx.x; i < NP_N; i += 1024) accN += (double)pN[i];
    for (int i = threadIdx.x; i < NP_G; i += 1024) accG += (double)pG[i];
    #pragma unroll
    for (int o = 32; o > 0; o >>= 1) {
        accN += __shfl_down(accN, o);
        accG += __shfl_down(accG, o);
    }
    __shared__ double sN[16], sG[16];
    int wave = threadIdx.x >> 6, lane = threadIdx.x & 63;
    if (lane == 0) { sN[wave] = accN; sG[wave] = accG; }
    __syncthreads();
    if (threadIdx.x == 0) {
        double tN = 0.0, tG = 0.0;
        #pragma unroll
        for (int w = 0; w < 16; ++w) { tN += sN[w]; tG += sG[w]; }
        double lncc = -(tN / (double)NPIX);
        double g2 = tG / (2.0 * GRAD_CNT);
        out[0] = (float)(lncc + g2);
    }
}

extern "C" void kernel_launch(void* const* d_in, const int* in_sizes, int n_in,
                              void* d_out, int out_size, void* d_ws, size_t ws_size,
                              hipStream_t stream) {
    const float* images = (const float*)d_in[0];
    const float* warps  = (const float*)d_in[1];
    float* out = (float*)d_out;

    __half* warped  = (__half*)d_ws;                          // NPIX halves
    float* fbase    = (float*)((char*)d_ws + (size_t)NPIX * 2);
    float* partialsN = fbase;                     // NP_N floats
    float* partialsG = partialsN + NP_N;          // NP_G floats
    float* tpart     = partialsG + NP_G;          // 4*HW floats

    warp_grad_kernel<<<dim3(K1_NT, NIMG), dim3(256), 0, stream>>>(
        images, warps, warped, partialsG);
    template_part_kernel<<<dim3(HW / 4 / 256, K2_SPLIT), dim3(256), 0, stream>>>(
        warped, tpart);
    lncc_kernel<<<dim3(K3_TILES, NIMG), dim3(256), 0, stream>>>(
        warped, tpart, partialsN);
    finalize_kernel<<<dim3(1), dim3(1024), 0, stream>>>(
        partialsN, partialsG, out);
}